// Round 9
// baseline (1736.076 us; speedup 1.0000x reference)
//
#include <hip/hip_runtime.h>
#include <stdint.h>

// Problem constants
#define NB      16
#define NPTS    4096
#define CPTS    64
#define NPOINT  1024
#define NSAMPLE 32
#define NROWS   (NB*NPOINT*NSAMPLE)   // 524288 rows of (b,s,k)

// f32 -> bf16 (RNE) and bf16 -> f32 (intermediates only; in/out are f32)
__device__ __forceinline__ unsigned short f2bf(float f){
  uint32_t u = __float_as_uint(f);
  uint32_t r = u + 0x7fffu + ((u>>16)&1u);
  return (unsigned short)(r>>16);
}
__device__ __forceinline__ float bf2f(unsigned short u){ return __uint_as_float(((uint32_t)u)<<16); }
__device__ __forceinline__ float lo16(uint32_t d){ return __uint_as_float(d<<16); }
__device__ __forceinline__ float hi16(uint32_t d){ return __uint_as_float(d & 0xffff0000u); }
__device__ __forceinline__ uint32_t pack2(float a, float b){ return ((uint32_t)f2bf(b)<<16) | (uint32_t)f2bf(a); }

// u64 cross-lane max via DPP (VALU) — row_shr 1/2/4/8 then row_bcast 15/31;
// lane63 ends with the wave max.  bound_ctrl=1 gives 0 for invalid lanes;
// 0 is a safe identity (all keys > 0).  Verified correct in R8 (passed).
#define DPP_PAIR(k, CTRL) \
  ( ((unsigned long long)(uint32_t)__builtin_amdgcn_update_dpp(0, (int)(uint32_t)((k)>>32), CTRL, 0xF, 0xF, true) << 32) \
    | (uint32_t)__builtin_amdgcn_update_dpp(0, (int)(uint32_t)(k), CTRL, 0xF, 0xF, true) )

// ---------------------------------------------------------------------------
// K1: Farthest point sampling.  R8 post-mortem: post-barrier serial chain
// (key-read -> compare -> s_x[fi] gather) was ~280cyc of the 1430cyc/iter.
// Now: best point COORDS tracked in registers during the scan (cndmask with
// constant indices only); after DPP reduce the owning lane (okey==wkey,
// unique via ~idx) writes (key,x,y,z) to its wave slot; post-barrier is one
// parallel 4-slot read + payload tournament.  No indexed LDS gather, no
// 48KB coordinate arrays.  Key=(f32bits(d)<<32)|~idx: dist>=0 so f32 bits
// order-isomorphic, ~idx = np.argmax first-occurrence tie-break.  Selection
// arithmetic unchanged => bit-identical indices vs R3-R8 passing versions.
// ---------------------------------------------------------------------------
__global__ __launch_bounds__(256) void fps_kernel(const float* __restrict__ xyz,
                                                  float* __restrict__ newxyz_f,
                                                  float* __restrict__ out){
  __shared__ uint4 s_A[2][4];   // {keyhi, keylo, xbits, ybits} per wave
  __shared__ float s_Z[2][4];
  const int b = blockIdx.x, t = threadIdx.x;
  const float* Xb = xyz + (size_t)b*NPTS*3;
  float px[16], py[16], pz[16], dd[16];
  #pragma unroll
  for (int i=0;i<16;++i){
    int n = t*16+i;
    px[i]=Xb[n*3+0]; py[i]=Xb[n*3+1]; pz[i]=Xb[n*3+2]; dd[i]=1e10f;
  }
  float cx=Xb[0], cy=Xb[1], cz=Xb[2];   // point 0 broadcast (L1 hit)
  if (t==0){
    size_t o=(size_t)b*NPOINT*3;   // sample 0 is index 0 (scan emits prior carry)
    newxyz_f[o]=cx; newxyz_f[o+1]=cy; newxyz_f[o+2]=cz;
    out[o]=cx; out[o+1]=cy; out[o+2]=cz;
  }
  __syncthreads();
  const int lane = t&63, wid = t>>6;
  for (int s=1;s<NPOINT;++s){
    float bv=-1.0f, bx=0.f, by=0.f, bz=0.f; int bi=0;
    #pragma unroll
    for (int i=0;i<16;++i){
      float dx=__fsub_rn(px[i],cx), dy=__fsub_rn(py[i],cy), dz=__fsub_rn(pz[i],cz);
      float d=__fadd_rn(__fadd_rn(__fmul_rn(dx,dx),__fmul_rn(dy,dy)),__fmul_rn(dz,dz));
      float nd=fminf(dd[i],d); dd[i]=nd;
      bool gt = nd>bv;                  // ascending i + strict > => lowest idx on tie
      bv = gt?nd:bv; bi = gt?(t*16+i):bi;
      bx = gt?px[i]:bx; by = gt?py[i]:by; bz = gt?pz[i]:bz;
    }
    const unsigned long long okey =
      ((unsigned long long)__float_as_uint(bv)<<32) | (uint32_t)(~bi);
    unsigned long long key = okey, o;
    o = DPP_PAIR(key,0x111); key = (o>key)?o:key;   // row_shr:1
    o = DPP_PAIR(key,0x112); key = (o>key)?o:key;   // row_shr:2
    o = DPP_PAIR(key,0x114); key = (o>key)?o:key;   // row_shr:4
    o = DPP_PAIR(key,0x118); key = (o>key)?o:key;   // row_shr:8
    o = DPP_PAIR(key,0x142); key = (o>key)?o:key;   // row_bcast:15
    o = DPP_PAIR(key,0x143); key = (o>key)?o:key;   // row_bcast:31
    uint32_t klo = (uint32_t)__builtin_amdgcn_readlane((int)(uint32_t)key, 63);
    uint32_t khi = (uint32_t)__builtin_amdgcn_readlane((int)(uint32_t)(key>>32), 63);
    const unsigned long long wkey = ((unsigned long long)khi<<32)|klo;
    const int buf = s&1;
    if (okey == wkey){                  // exactly one lane per wave (idx unique)
      s_A[buf][wid] = make_uint4(khi, klo, __float_as_uint(bx), __float_as_uint(by));
      s_Z[buf][wid] = bz;
    }
    __syncthreads();
    uint4 A0=s_A[buf][0], A1=s_A[buf][1], A2=s_A[buf][2], A3=s_A[buf][3];
    float Z0=s_Z[buf][0], Z1=s_Z[buf][1], Z2=s_Z[buf][2], Z3=s_Z[buf][3];
    unsigned long long k0=((unsigned long long)A0.x<<32)|A0.y;
    unsigned long long k1=((unsigned long long)A1.x<<32)|A1.y;
    unsigned long long k2=((unsigned long long)A2.x<<32)|A2.y;
    unsigned long long k3=((unsigned long long)A3.x<<32)|A3.y;
    bool cA = k1>k0;
    unsigned long long kA = cA?k1:k0;
    uint32_t xA = cA?A1.z:A0.z, yA = cA?A1.w:A0.w; float zA = cA?Z1:Z0;
    bool cB = k3>k2;
    unsigned long long kB = cB?k3:k2;
    uint32_t xB = cB?A3.z:A2.z, yB = cB?A3.w:A2.w; float zB = cB?Z3:Z2;
    bool cF = kB>kA;
    cx = __uint_as_float(cF?xB:xA);
    cy = __uint_as_float(cF?yB:yA);
    cz = cF?zB:zA;
    if (t==0){
      size_t o2=((size_t)b*NPOINT+s)*3;
      newxyz_f[o2]=cx; newxyz_f[o2+1]=cy; newxyz_f[o2+2]=cz;
      out[o2]=cx; out[o2+1]=cy; out[o2+2]=cz;
    }
    // no 2nd barrier: next iter writes the OTHER slot buffer; reaching that
    // write requires passing this barrier, which all waves' reads precede.
  }
}

// ---------------------------------------------------------------------------
// K2: Ball query.  REWRITE (R8): old version used 4096 blocks, each staging
// the same 48KB batch xyz for only 4 centers (256x redundant).  Now 256
// blocks (16/batch): coalesced AoS stage once, each wave scans 16 centers
// sequentially.  Ballot + prefix-popcount core and distance bit-arithmetic
// unchanged => identical indices.  AoS LDS reads are lane-stride-3 dwords
// -> 2-way bank aliasing only (free).
// ---------------------------------------------------------------------------
__global__ __launch_bounds__(256) void ballq_kernel(const float* __restrict__ xyz,
                                                    const float* __restrict__ newxyz_f,
                                                    int* __restrict__ ballidx){
  __shared__ float s_p[NPTS*3];       // 48 KB AoS
  __shared__ int s_list[4][NSAMPLE];
  const int b  = blockIdx.x >> 4;     // 16 blocks per batch
  const int cg = blockIdx.x & 15;     // this block's 64 centers
  const int t = threadIdx.x;
  const float* Xb = xyz + (size_t)b*NPTS*3;
  for (int i=t;i<NPTS*3;i+=256) s_p[i]=Xb[i];
  __syncthreads();
  const int lane = t&63, wid = t>>6;
  const float R2 = 0.04f;             // f32(0.2**2), NEP-50 weak-scalar promotion
  for (int ci=0; ci<16; ++ci){
    const int s = cg*64 + wid*16 + ci;
    size_t co = ((size_t)b*NPOINT+s)*3;
    const float cx=newxyz_f[co], cy=newxyz_f[co+1], cz=newxyz_f[co+2];
    int count = 0;
    for (int j0=0; j0<NPTS && count<NSAMPLE; j0+=64){
      int j=j0+lane;
      float dx=__fsub_rn(cx,s_p[3*j]), dy=__fsub_rn(cy,s_p[3*j+1]), dz=__fsub_rn(cz,s_p[3*j+2]);
      float sq=__fadd_rn(__fadd_rn(__fmul_rn(dx,dx),__fmul_rn(dy,dy)),__fmul_rn(dz,dz));
      bool in = !(sq > R2);
      unsigned long long m = __ballot(in);
      int before = __popcll(m & ((1ull<<lane)-1ull));
      int pos = count + before;
      if (in && pos < NSAMPLE) s_list[wid][pos] = j;
      count += __popcll(m);
    }
    int c = count < NSAMPLE ? count : NSAMPLE;   // >=1: center is in its own ball
    int first = s_list[wid][0];
    if (lane >= c && lane < NSAMPLE) s_list[wid][lane] = first;
    if (lane < NSAMPLE) ballidx[((size_t)b*NPOINT+s)*NSAMPLE + lane] = s_list[wid][lane];
  }
}

// ---------------------------------------------------------------------------
// K3: layer 1 — gather + concat + (67 -> 64) matmul + bias -> h (bf16).
// LDS-staged coalesced gather; 2 threads per row, acc[16] (no private arrays
// with dynamic indexing -> no scratch demotion).
// ---------------------------------------------------------------------------
#define L1_STRIDE 71
__global__ __launch_bounds__(256,3) void layer1_kernel(const float* __restrict__ xyz,
    const float* __restrict__ points, const int* __restrict__ ballidx,
    const float* __restrict__ newxyz_f, const float* __restrict__ w0,
    const float* __restrict__ b0, unsigned short* __restrict__ h){
  __shared__ float s_w[67*32];            // [c][o_local], c: 0..63=points, 64..66=xyz
  __shared__ float s_b[32];
  __shared__ float s_x[128*L1_STRIDE];    // 128 rows x 71 (67 used)
  __shared__ int   s_j[128];
  const int t = threadIdx.x;
  const int tile = blockIdx.x >> 1;       // 4096 tiles of 128 rows
  const int half = blockIdx.x & 1;        // output channels [half*32, half*32+32)
  const int tileBase = tile*128;
  for (int i=t;i<67*32;i+=256){
    int c=i>>5, oL=i&31;
    int srcc = (c<64) ? (c+3) : (c-64);
    s_w[i] = w0[(half*32+oL)*67 + srcc];
  }
  if (t<32) s_b[t]=b0[half*32+t];
  if (t<128) s_j[t]=ballidx[tileBase+t];
  __syncthreads();
  #pragma unroll
  for (int it=0; it<8; ++it){
    int r = it*16 + (t>>4);
    int row = tileBase + r;
    int bb = row >> 15;                   // 32768 rows per batch
    int j  = s_j[r];
    float4 pv = *(const float4*)(points + ((size_t)bb*NPTS + (size_t)j)*CPTS + (t&15)*4);
    float* xr = s_x + r*L1_STRIDE + (t&15)*4;
    xr[0]=pv.x; xr[1]=pv.y; xr[2]=pv.z; xr[3]=pv.w;
  }
  if (t<128){
    int row = tileBase + t;
    int bs  = row >> 5;
    int bb  = bs >> 10;
    int j   = s_j[t];
    const float* xr = xyz + ((size_t)bb*NPTS + (size_t)j)*3;
    const float* cp = newxyz_f + (size_t)bs*3;
    float* xd = s_x + t*L1_STRIDE + 64;
    xd[0]=(xr[0]-cp[0])/0.2f; xd[1]=(xr[1]-cp[1])/0.2f; xd[2]=(xr[2]-cp[2])/0.2f;
  }
  __syncthreads();
  const int r    = t & 127;
  const int osub = (t>>7)*16;
  const float* xp = s_x + r*L1_STRIDE;
  float acc[16];
  #pragma unroll
  for (int o=0;o<16;++o) acc[o]=0.0f;
  for (int c=0;c<67;++c){
    float xv = xp[c];
    const float4* wr=(const float4*)(s_w + c*32 + osub);
    #pragma unroll
    for (int q=0;q<4;++q){ float4 w=wr[q];
      acc[4*q+0]=fmaf(xv,w.x,acc[4*q+0]); acc[4*q+1]=fmaf(xv,w.y,acc[4*q+1]);
      acc[4*q+2]=fmaf(xv,w.z,acc[4*q+2]); acc[4*q+3]=fmaf(xv,w.w,acc[4*q+3]); }
  }
  uint4* od=(uint4*)(h + (size_t)(tileBase+r)*64 + half*32 + osub);
  #pragma unroll
  for (int q=0;q<2;++q){
    uint4 v;
    v.x=pack2(acc[8*q+0]+s_b[osub+8*q+0], acc[8*q+1]+s_b[osub+8*q+1]);
    v.y=pack2(acc[8*q+2]+s_b[osub+8*q+2], acc[8*q+3]+s_b[osub+8*q+3]);
    v.z=pack2(acc[8*q+4]+s_b[osub+8*q+4], acc[8*q+5]+s_b[osub+8*q+5]);
    v.w=pack2(acc[8*q+6]+s_b[osub+8*q+6], acc[8*q+7]+s_b[osub+8*q+7]);
    od[q]=v;
  }
}

// ---------------------------------------------------------------------------
// Stats over h (bf16, C=64): per-channel sum/sumsq, coalesced uint4 reads,
// LDS block-reduce, one atomicAdd pair per channel per block.
// ---------------------------------------------------------------------------
__global__ __launch_bounds__(256) void stats64_kernel(const unsigned short* __restrict__ h,
                                                      float* __restrict__ st){
  __shared__ float s_red[4][64][8], s_red2[4][64][8];
  const int t=threadIdx.x, lane=t&63, wid=t>>6;
  const int gw = blockIdx.x*4+wid;         // 512 blocks -> 0..2047 waves
  const int rsub = lane>>3;
  float sm[8], sq[8];
  #pragma unroll
  for (int j=0;j<8;++j){ sm[j]=0.f; sq[j]=0.f; }
  for (int it=0; it<32; ++it){
    size_t row = (size_t)gw*256 + it*8 + rsub;
    const uint4* p = (const uint4*)(h + row*64) + (lane&7);
    uint4 v = *p;
    uint32_t ds4[4]={v.x,v.y,v.z,v.w};
    #pragma unroll
    for (int dj=0;dj<4;++dj){
      float a=lo16(ds4[dj]), b2=hi16(ds4[dj]);
      sm[2*dj]+=a;   sq[2*dj]  =fmaf(a,a,sq[2*dj]);
      sm[2*dj+1]+=b2; sq[2*dj+1]=fmaf(b2,b2,sq[2*dj+1]);
    }
  }
  #pragma unroll
  for (int j=0;j<8;++j){ s_red[wid][lane][j]=sm[j]; s_red2[wid][lane][j]=sq[j]; }
  __syncthreads();
  if (t<64){
    float ts=0.f,tq=0.f;
    #pragma unroll
    for (int w=0;w<4;++w)
      #pragma unroll
      for (int m=0;m<8;++m){ int l=(t>>3)+8*m; ts+=s_red[w][l][t&7]; tq+=s_red2[w][l][t&7]; }
    atomicAdd(&st[t*2], ts); atomicAdd(&st[t*2+1], tq);
  }
}

// ---------------------------------------------------------------------------
// K4: layer 2 — (64 -> 64) matmul + bias, in place.  BN(stats0)+ReLU applied
// while staging 128 rows into an LDS tile (stride 65); 2 threads per row,
// acc[32] fully unrolled; no private arrays -> no scratch demotion.
// ---------------------------------------------------------------------------
__global__ __launch_bounds__(256,3) void layer2_kernel(unsigned short* __restrict__ h,
    const float* __restrict__ st, const float* __restrict__ g,
    const float* __restrict__ be, const float* __restrict__ w1,
    const float* __restrict__ b1){
  __shared__ float s_w[64*64];            // 16 KB  [c][o]
  __shared__ float s_x[128*65];           // 33.3 KB
  __shared__ float s_b[64], s_scale[64], s_shift[64];
  const int t=threadIdx.x;
  const int tileBase = blockIdx.x*128;    // 4096 blocks
  for (int i=t;i<64*64;i+=256){ int c=i>>6, o=i&63; s_w[i]=w1[o*64+c]; }
  if (t<64){
    s_b[t]=b1[t];
    float mu=st[t*2]*(1.0f/NROWS);
    float var=st[t*2+1]*(1.0f/NROWS)-mu*mu;
    float inv=1.0f/sqrtf(var+1e-5f);
    s_scale[t]=inv*g[t]; s_shift[t]=be[t]-mu*inv*g[t];
  }
  __syncthreads();
  #pragma unroll
  for (int it=0; it<4; ++it){
    int idx = it*256 + t;
    int r = idx>>3, seg = idx&7;
    uint4 v = *((const uint4*)(h + (size_t)(tileBase+r)*64) + seg);
    float* xd = s_x + r*65 + seg*8;
    uint32_t ds4[4]={v.x,v.y,v.z,v.w};
    #pragma unroll
    for (int dj=0;dj<4;++dj){
      int c = seg*8 + dj*2;
      xd[dj*2+0]=fmaxf(fmaf(lo16(ds4[dj]),s_scale[c],  s_shift[c]),  0.0f);
      xd[dj*2+1]=fmaxf(fmaf(hi16(ds4[dj]),s_scale[c+1],s_shift[c+1]),0.0f);
    }
  }
  __syncthreads();
  const int r    = t & 127;
  const int osub = (t>>7)*32;
  const float* xp = s_x + r*65;
  float acc[32];
  #pragma unroll
  for (int o=0;o<32;++o) acc[o]=0.0f;
  for (int c=0;c<64;++c){
    float xv = xp[c];
    const float4* wr=(const float4*)(s_w + c*64 + osub);
    #pragma unroll
    for (int q=0;q<8;++q){ float4 w=wr[q];
      acc[4*q+0]=fmaf(xv,w.x,acc[4*q+0]); acc[4*q+1]=fmaf(xv,w.y,acc[4*q+1]);
      acc[4*q+2]=fmaf(xv,w.z,acc[4*q+2]); acc[4*q+3]=fmaf(xv,w.w,acc[4*q+3]); }
  }
  uint4* od=(uint4*)(h + (size_t)(tileBase+r)*64 + osub);
  #pragma unroll
  for (int q=0;q<4;++q){
    uint4 v;
    v.x=pack2(acc[8*q+0]+s_b[osub+8*q+0], acc[8*q+1]+s_b[osub+8*q+1]);
    v.y=pack2(acc[8*q+2]+s_b[osub+8*q+2], acc[8*q+3]+s_b[osub+8*q+3]);
    v.z=pack2(acc[8*q+4]+s_b[osub+8*q+4], acc[8*q+5]+s_b[osub+8*q+5]);
    v.w=pack2(acc[8*q+6]+s_b[osub+8*q+6], acc[8*q+7]+s_b[osub+8*q+7]);
    od[q]=v;
  }
}

// ---------------------------------------------------------------------------
// K5: layer 3 fused — BN(stats1)+ReLU (at stage time), (64 -> 128) matmul +
// bias, per-s max/min over K=32 + BN3 partial sums.  One 32-row s-group per
// block (16384 blocks); x tile stride 65; out tile f32 stride 133; 8 threads
// per row x acc[16]; partial sums to part[] (atomic-free), reduced by K5b.
// ---------------------------------------------------------------------------
__global__ __launch_bounds__(256,3) void layer3mm_kernel(const unsigned short* __restrict__ h,
    const float* __restrict__ st, const float* __restrict__ g,
    const float* __restrict__ be, const float* __restrict__ w2,
    const float* __restrict__ b2, float* __restrict__ mm, float* __restrict__ part){
  __shared__ unsigned short s_w[64*128];  // 16 KB  s_w[c*128+o]=bf16(w2[o][c])
  __shared__ float s_x[32*65];            // 8.3 KB
  __shared__ float s_o[32*133];           // 17 KB
  __shared__ float s_scale[64], s_shift[64], s_b2[128];
  const int t=threadIdx.x;
  const int sgBase = blockIdx.x*32;       // row base of this s-group
  for (int i=t;i<64*128;i+=256){ int c=i>>7, o=i&127; s_w[i]=f2bf(w2[o*64+c]); }
  if (t<64){
    float mu=st[t*2]*(1.0f/NROWS);
    float var=st[t*2+1]*(1.0f/NROWS)-mu*mu;
    float inv=1.0f/sqrtf(var+1e-5f);
    s_scale[t]=inv*g[t]; s_shift[t]=be[t]-mu*inv*g[t];
  }
  if (t<128) s_b2[t]=b2[t];
  __syncthreads();
  {
    int r = t>>3, seg = t&7;
    uint4 v = *((const uint4*)(h + (size_t)(sgBase+r)*64) + seg);
    float* xd = s_x + r*65 + seg*8;
    uint32_t ds4[4]={v.x,v.y,v.z,v.w};
    #pragma unroll
    for (int dj=0;dj<4;++dj){
      int c = seg*8 + dj*2;
      xd[dj*2+0]=fmaxf(fmaf(lo16(ds4[dj]),s_scale[c],  s_shift[c]),  0.0f);
      xd[dj*2+1]=fmaxf(fmaf(hi16(ds4[dj]),s_scale[c+1],s_shift[c+1]),0.0f);
    }
  }
  __syncthreads();
  {
    const int r    = t & 31;
    const int osub = (t>>5)*16;
    const float* xp = s_x + r*65;
    float acc[16];
    #pragma unroll
    for (int o=0;o<16;++o) acc[o]=0.0f;
    for (int c=0;c<64;++c){
      float xv = xp[c];
      const uint4* wr=(const uint4*)(s_w + c*128 + osub);
      #pragma unroll
      for (int q=0;q<2;++q){
        uint4 wu=wr[q];
        acc[8*q+0]=fmaf(xv,lo16(wu.x),acc[8*q+0]); acc[8*q+1]=fmaf(xv,hi16(wu.x),acc[8*q+1]);
        acc[8*q+2]=fmaf(xv,lo16(wu.y),acc[8*q+2]); acc[8*q+3]=fmaf(xv,hi16(wu.y),acc[8*q+3]);
        acc[8*q+4]=fmaf(xv,lo16(wu.z),acc[8*q+4]); acc[8*q+5]=fmaf(xv,hi16(wu.z),acc[8*q+5]);
        acc[8*q+6]=fmaf(xv,lo16(wu.w),acc[8*q+6]); acc[8*q+7]=fmaf(xv,hi16(wu.w),acc[8*q+7]);
      }
    }
    float* op = s_o + r*133 + osub;
    #pragma unroll
    for (int o=0;o<16;++o) op[o] = acc[o] + s_b2[osub+o];
  }
  __syncthreads();
  if (t<128){
    float mx=-3e38f, mn=3e38f, sm=0.f, sq=0.f;
    #pragma unroll
    for (int r=0;r<32;++r){
      float v = s_o[r*133 + t];
      mx=fmaxf(mx,v); mn=fminf(mn,v); sm+=v; sq=fmaf(v,v,sq);
    }
    float* mp = mm + (size_t)blockIdx.x*256;
    mp[t]     = mx;
    mp[128+t] = mn;
    part[(size_t)blockIdx.x*256 + t]       = sm;
    part[(size_t)blockIdx.x*256 + 128 + t] = sq;
  }
}

// ---------------------------------------------------------------------------
// K5b: reduce part[16384][256] -> st2 (interleaved {sum,sumsq} per channel).
// ---------------------------------------------------------------------------
__global__ __launch_bounds__(256) void reduce_kernel(const float* __restrict__ part,
                                                     float* __restrict__ st2){
  const int t=threadIdx.x;
  const int base = blockIdx.x*64;
  float acc=0.f;
  for (int r=0;r<64;++r) acc += part[(size_t)(base+r)*256 + t];
  if (t<128) atomicAdd(&st2[t*2], acc);
  else       atomicAdd(&st2[(t-128)*2+1], acc);
}

// ---------------------------------------------------------------------------
// K6: BN(stats2) on max (or min if scale<0) + ReLU -> new_points (f32).
// ---------------------------------------------------------------------------
__global__ __launch_bounds__(256) void final_kernel(const float* __restrict__ mm,
    const float* __restrict__ st, const float* __restrict__ g,
    const float* __restrict__ be, float* __restrict__ out){
  __shared__ float s_scale[128], s_shift[128];
  const int t=threadIdx.x;
  if (t<128){
    float mu=st[t*2]*(1.0f/NROWS);
    float var=st[t*2+1]*(1.0f/NROWS)-mu*mu;
    float inv=1.0f/sqrtf(var+1e-5f);
    s_scale[t]=inv*g[t]; s_shift[t]=be[t]-mu*inv*g[t];
  }
  __syncthreads();
  const int idx = blockIdx.x*256+t;       // bs*128 + ch
  const int ch = idx & 127, bs = idx >> 7;
  float sc=s_scale[ch];
  float v = (sc>=0.f)? mm[(size_t)bs*256+ch] : mm[(size_t)bs*256+128+ch];
  out[(size_t)NB*NPOINT*3 + idx] = fmaxf(fmaf(v,sc,s_shift[ch]),0.0f);
}

// ---------------------------------------------------------------------------
extern "C" void kernel_launch(void* const* d_in, const int* in_sizes, int n_in,
                              void* d_out, int out_size, void* d_ws, size_t ws_size,
                              hipStream_t stream) {
  const float* xyz    = (const float*)d_in[0];
  const float* points = (const float*)d_in[1];
  const float* w0 = (const float*)d_in[2];
  const float* b0 = (const float*)d_in[3];
  const float* g0 = (const float*)d_in[4];
  const float* be0= (const float*)d_in[5];
  const float* w1 = (const float*)d_in[6];
  const float* b1 = (const float*)d_in[7];
  const float* g1 = (const float*)d_in[8];
  const float* be1= (const float*)d_in[9];
  const float* w2 = (const float*)d_in[10];
  const float* b2 = (const float*)d_in[11];
  const float* g2 = (const float*)d_in[12];
  const float* be2= (const float*)d_in[13];
  float* out = (float*)d_out;             // f32 output per reference dtype
  char* ws = (char*)d_ws;

  // ws layout (100 MiB total):
  //   [0,        196608)    newxyz_f (16,1024,3) f32
  //   [196608,   2293760)   ballidx  (16,1024,32) i32
  //   [2293760,  2296832)   stats: 3 slots x 256 f32 {sum,sumsq interleaved}
  //   [4 MiB,    20 MiB)    mm: (16384, {max,min}, 128) f32
  //   [20 MiB,   84 MiB)    h: (524288, 64) bf16 — h1, then h2 in place
  //   [84 MiB,   100 MiB)   part: (16384, 256) f32 BN3 partial sums
  float* newxyz_f = (float*)(ws);
  int*   ballidx  = (int*)(ws + 196608);
  float* stats    = (float*)(ws + 2293760);
  float* mm       = (float*)(ws + 4194304);
  unsigned short* h = (unsigned short*)(ws + 20971520);
  float* part     = (float*)(ws + 88080384);

  hipMemsetAsync(stats, 0, 3072, stream);
  hipLaunchKernelGGL(fps_kernel,     dim3(NB),    dim3(256), 0, stream, xyz, newxyz_f, out);
  hipLaunchKernelGGL(ballq_kernel,   dim3(256),   dim3(256), 0, stream, xyz, newxyz_f, ballidx);
  hipLaunchKernelGGL(layer1_kernel,  dim3(8192),  dim3(256), 0, stream,
                     xyz, points, ballidx, newxyz_f, w0, b0, h);
  hipLaunchKernelGGL(stats64_kernel, dim3(512),   dim3(256), 0, stream, h, stats + 0);
  hipLaunchKernelGGL(layer2_kernel,  dim3(4096),  dim3(256), 0, stream,
                     h, stats + 0, g0, be0, w1, b1);
  hipLaunchKernelGGL(stats64_kernel, dim3(512),   dim3(256), 0, stream, h, stats + 256);
  hipLaunchKernelGGL(layer3mm_kernel,dim3(16384), dim3(256), 0, stream,
                     h, stats + 256, g1, be1, w2, b2, mm, part);
  hipLaunchKernelGGL(reduce_kernel,  dim3(256),   dim3(256), 0, stream, part, stats + 512);
  hipLaunchKernelGGL(final_kernel,   dim3(8192),  dim3(256), 0, stream,
                     mm, stats + 512, g2, be2, out);
}